// Round 2
// baseline (802.214 us; speedup 1.0000x reference)
//
#include <hip/hip_runtime.h>
#include <math.h>

#define EPS_LN 1e-5f
#define TPTS 65536

struct Params {
  const float *W0,*b0,*W1,*b1,*W2,*b2,*W3,*b3,*W4,*b4,*W5,*b5,*W6,*b6;
  const float *g0,*be0,*g1,*be1,*g2,*be2,*g3,*be3,*g4,*be4,*g5,*be5;
};

// ---------- order-preserving float<->uint for atomic min/max ----------
__device__ __forceinline__ unsigned enc_f(float f) {
  unsigned u = __float_as_uint(f);
  return (u & 0x80000000u) ? ~u : (u | 0x80000000u);
}
__device__ __forceinline__ float dec_f(unsigned k) {
  unsigned u = (k & 0x80000000u) ? (k ^ 0x80000000u) : ~k;
  return __uint_as_float(u);
}

// ---------- fully-unrolled tiny-MLP building blocks (all static indexing) ----------
template<int IN, int OUT>
__device__ __forceinline__ void linear_full(const float* hin, const float* __restrict__ W,
                                            const float* __restrict__ b, float* hout) {
  #pragma unroll
  for (int j = 0; j < OUT; ++j) hout[j] = b[j];
  #pragma unroll
  for (int i = 0; i < IN; ++i) {
    float v = hin[i];
    #pragma unroll
    for (int j = 0; j < OUT; ++j) hout[j] = fmaf(v, W[i * OUT + j], hout[j]);
  }
}

template<int D>
__device__ __forceinline__ void ln_relu(float* h, const float* __restrict__ g,
                                        const float* __restrict__ be) {
  float s0 = 0.f, s1 = 0.f, s2 = 0.f, s3 = 0.f;
  #pragma unroll
  for (int j = 0; j < D; j += 4) { s0 += h[j]; s1 += h[j+1]; s2 += h[j+2]; s3 += h[j+3]; }
  float m = (s0 + s1) + (s2 + s3);
  m *= (1.0f / (float)D);
  float v0 = 0.f, v1 = 0.f, v2 = 0.f, v3 = 0.f;
  #pragma unroll
  for (int j = 0; j < D; j += 4) {
    float d0 = h[j] - m, d1 = h[j+1] - m, d2 = h[j+2] - m, d3 = h[j+3] - m;
    v0 = fmaf(d0, d0, v0); v1 = fmaf(d1, d1, v1);
    v2 = fmaf(d2, d2, v2); v3 = fmaf(d3, d3, v3);
  }
  float var = ((v0 + v1) + (v2 + v3)) * (1.0f / (float)D);
  float sc = rsqrtf(var + EPS_LN);
  #pragma unroll
  for (int j = 0; j < D; ++j) {
    float t = (h[j] - m) * sc;
    t = fmaf(t, g[j], be[j]);
    h[j] = fmaxf(t, 0.0f);
  }
}

__device__ __forceinline__ float eval_chain(float x, const Params& P) {
  float a0[16];
  #pragma unroll
  for (int j = 0; j < 16; ++j) a0[j] = fmaf(x, P.W0[j], P.b0[j]);
  ln_relu<16>(a0, P.g0, P.be0);
  float a1[32]; linear_full<16, 32>(a0, P.W1, P.b1, a1); ln_relu<32>(a1, P.g1, P.be1);
  float a2[64]; linear_full<32, 64>(a1, P.W2, P.b2, a2); ln_relu<64>(a2, P.g2, P.be2);
  float a3[128]; linear_full<64, 128>(a2, P.W3, P.b3, a3); ln_relu<128>(a3, P.g3, P.be3);
  float a4[64]; linear_full<128, 64>(a3, P.W4, P.b4, a4); ln_relu<64>(a4, P.g4, P.be4);
  float a5[32]; linear_full<64, 32>(a4, P.W5, P.b5, a5); ln_relu<32>(a5, P.g5, P.be5);
  float y0 = P.b6[0], y1 = 0.f, y2 = 0.f, y3 = 0.f;
  #pragma unroll
  for (int i = 0; i < 32; i += 4) {
    y0 = fmaf(a5[i],   P.W6[i],   y0);
    y1 = fmaf(a5[i+1], P.W6[i+1], y1);
    y2 = fmaf(a5[i+2], P.W6[i+2], y2);
    y3 = fmaf(a5[i+3], P.W6[i+3], y3);
  }
  return (y0 + y1) + (y2 + y3);
}

// ---------- range derivation (identical fp32 arithmetic in build & lookup) ----------
__device__ __forceinline__ void get_range(const unsigned* __restrict__ mm,
                                          float& lo, float& step, float& istep) {
  float fmin = dec_f(mm[0]) - 1e-3f;
  float fmax = dec_f(mm[1]) + 1e-3f;
  lo = fmin;
  float span = fmax - fmin;
  step  = span * (1.0f / (float)(TPTS - 1));
  istep = (float)(TPTS - 1) / span;
}

// ---------- kernels ----------
__global__ void init_kernel(unsigned* mm) {
  mm[0] = 0xFFFFFFFFu;  // min key
  mm[1] = 0u;           // max key
}

__global__ __launch_bounds__(256) void minmax_kernel(const float* __restrict__ x,
                                                     unsigned* mm, int n) {
  int tid = blockIdx.x * blockDim.x + threadIdx.x;
  int stride = gridDim.x * blockDim.x;
  float lmin = 3.0e38f, lmax = -3.0e38f;
  for (int i = tid * 4; i + 3 < n; i += stride * 4) {
    float4 v = *reinterpret_cast<const float4*>(x + i);
    lmin = fminf(lmin, fminf(fminf(v.x, v.y), fminf(v.z, v.w)));
    lmax = fmaxf(lmax, fmaxf(fmaxf(v.x, v.y), fmaxf(v.z, v.w)));
  }
  if (tid == 0) {  // tail if n % 4 != 0
    for (int i = n & ~3; i < n; ++i) {
      lmin = fminf(lmin, x[i]);
      lmax = fmaxf(lmax, x[i]);
    }
  }
  #pragma unroll
  for (int off = 32; off > 0; off >>= 1) {
    lmin = fminf(lmin, __shfl_xor(lmin, off));
    lmax = fmaxf(lmax, __shfl_xor(lmax, off));
  }
  if ((threadIdx.x & 63) == 0) {
    atomicMin(&mm[0], enc_f(lmin));
    atomicMax(&mm[1], enc_f(lmax));
  }
}

__global__ __launch_bounds__(256, 1) void build_kernel(float* __restrict__ table,
                                                       const unsigned* __restrict__ mm,
                                                       Params P) {
  int idx = blockIdx.x * blockDim.x + threadIdx.x;
  float lo, step, istep;
  get_range(mm, lo, step, istep);
  float x = fmaf((float)idx, step, lo);
  table[idx] = eval_chain(x, P);
}

__device__ __forceinline__ float interp(float xv, float lo, float istep,
                                        const float* __restrict__ t) {
  float tt = (xv - lo) * istep;
  tt = fminf(fmaxf(tt, 0.0f), (float)(TPTS - 1));
  int i = (int)tt;
  if (i > TPTS - 2) i = TPTS - 2;
  float f = tt - (float)i;
  float t0 = t[i], t1 = t[i + 1];
  return fmaf(f, t1 - t0, t0);
}

__global__ __launch_bounds__(256) void lookup_kernel(const float* __restrict__ x,
                                                     const float* __restrict__ table,
                                                     const unsigned* __restrict__ mm,
                                                     float* __restrict__ out, int n) {
  float lo, step, istep;
  get_range(mm, lo, step, istep);
  int tid = blockIdx.x * blockDim.x + threadIdx.x;
  int stride = gridDim.x * blockDim.x;
  for (int i = tid * 4; i + 3 < n; i += stride * 4) {
    float4 v = *reinterpret_cast<const float4*>(x + i);
    float4 r;
    r.x = interp(v.x, lo, istep, table);
    r.y = interp(v.y, lo, istep, table);
    r.z = interp(v.z, lo, istep, table);
    r.w = interp(v.w, lo, istep, table);
    *reinterpret_cast<float4*>(out + i) = r;
  }
  if (tid == 0) {  // tail if n % 4 != 0
    for (int i = n & ~3; i < n; ++i) out[i] = interp(x[i], lo, istep, table);
  }
}

// Fallback: direct per-element evaluation (used only if workspace too small)
__global__ __launch_bounds__(256, 1) void direct_kernel(const float* __restrict__ x,
                                                        Params P, float* __restrict__ out,
                                                        int n) {
  int tid = blockIdx.x * blockDim.x + threadIdx.x;
  int stride = gridDim.x * blockDim.x;
  for (int i = tid; i < n; i += stride) out[i] = eval_chain(x[i], P);
}

extern "C" void kernel_launch(void* const* d_in, const int* in_sizes, int n_in,
                              void* d_out, int out_size, void* d_ws, size_t ws_size,
                              hipStream_t stream) {
  const float* x = (const float*)d_in[0];
  Params P;
  P.W0 = (const float*)d_in[1];  P.b0 = (const float*)d_in[2];
  P.W1 = (const float*)d_in[3];  P.b1 = (const float*)d_in[4];
  P.W2 = (const float*)d_in[5];  P.b2 = (const float*)d_in[6];
  P.W3 = (const float*)d_in[7];  P.b3 = (const float*)d_in[8];
  P.W4 = (const float*)d_in[9];  P.b4 = (const float*)d_in[10];
  P.W5 = (const float*)d_in[11]; P.b5 = (const float*)d_in[12];
  P.W6 = (const float*)d_in[13]; P.b6 = (const float*)d_in[14];
  P.g0 = (const float*)d_in[15]; P.be0 = (const float*)d_in[16];
  P.g1 = (const float*)d_in[17]; P.be1 = (const float*)d_in[18];
  P.g2 = (const float*)d_in[19]; P.be2 = (const float*)d_in[20];
  P.g3 = (const float*)d_in[21]; P.be3 = (const float*)d_in[22];
  P.g4 = (const float*)d_in[23]; P.be4 = (const float*)d_in[24];
  P.g5 = (const float*)d_in[25]; P.be5 = (const float*)d_in[26];

  int n = in_sizes[0];
  float* out = (float*)d_out;

  size_t need = 256 + (size_t)TPTS * sizeof(float);
  if (ws_size < need) {
    direct_kernel<<<2048, 256, 0, stream>>>(x, P, out, n);
    return;
  }

  unsigned* mm = (unsigned*)d_ws;
  float* table = (float*)((char*)d_ws + 256);

  init_kernel<<<1, 1, 0, stream>>>(mm);
  minmax_kernel<<<512, 256, 0, stream>>>(x, mm, n);
  build_kernel<<<TPTS / 256, 256, 0, stream>>>(table, mm, P);
  lookup_kernel<<<1024, 256, 0, stream>>>(x, table, mm, out, n);
}

// Round 3
// 483.929 us; speedup vs baseline: 1.6577x; 1.6577x over previous
//
#include <hip/hip_runtime.h>
#include <math.h>

#define EPS_LN 1e-5f
#define TPTS 65536

struct Params {
  const float *W0,*b0,*W1,*b1,*W2,*b2,*W3,*b3,*W4,*b4,*W5,*b5,*W6,*b6;
  const float *g0,*be0,*g1,*be1,*g2,*be2,*g3,*be3,*g4,*be4,*g5,*be5;
};

// ---------- order-preserving float<->uint for atomic min/max ----------
__device__ __forceinline__ unsigned enc_f(float f) {
  unsigned u = __float_as_uint(f);
  return (u & 0x80000000u) ? ~u : (u | 0x80000000u);
}
__device__ __forceinline__ float dec_f(unsigned k) {
  unsigned u = (k & 0x80000000u) ? (k ^ 0x80000000u) : ~k;
  return __uint_as_float(u);
}

// ---------- fully-unrolled tiny-MLP building blocks (all static indexing) ----------
template<int IN, int OUT>
__device__ __forceinline__ void linear_full(const float* hin, const float* __restrict__ W,
                                            const float* __restrict__ b, float* hout) {
  #pragma unroll
  for (int j = 0; j < OUT; ++j) hout[j] = b[j];
  #pragma unroll
  for (int i = 0; i < IN; ++i) {
    float v = hin[i];
    #pragma unroll
    for (int j = 0; j < OUT; ++j) hout[j] = fmaf(v, W[i * OUT + j], hout[j]);
  }
}

template<int D>
__device__ __forceinline__ void ln_relu(float* h, const float* __restrict__ g,
                                        const float* __restrict__ be) {
  float s0 = 0.f, s1 = 0.f, s2 = 0.f, s3 = 0.f;
  #pragma unroll
  for (int j = 0; j < D; j += 4) { s0 += h[j]; s1 += h[j+1]; s2 += h[j+2]; s3 += h[j+3]; }
  float m = (s0 + s1) + (s2 + s3);
  m *= (1.0f / (float)D);
  float v0 = 0.f, v1 = 0.f, v2 = 0.f, v3 = 0.f;
  #pragma unroll
  for (int j = 0; j < D; j += 4) {
    float d0 = h[j] - m, d1 = h[j+1] - m, d2 = h[j+2] - m, d3 = h[j+3] - m;
    v0 = fmaf(d0, d0, v0); v1 = fmaf(d1, d1, v1);
    v2 = fmaf(d2, d2, v2); v3 = fmaf(d3, d3, v3);
  }
  float var = ((v0 + v1) + (v2 + v3)) * (1.0f / (float)D);
  float sc = rsqrtf(var + EPS_LN);
  #pragma unroll
  for (int j = 0; j < D; ++j) {
    float t = (h[j] - m) * sc;
    t = fmaf(t, g[j], be[j]);
    h[j] = fmaxf(t, 0.0f);
  }
}

__device__ __forceinline__ float eval_chain(float x, const Params& P) {
  float a0[16];
  #pragma unroll
  for (int j = 0; j < 16; ++j) a0[j] = fmaf(x, P.W0[j], P.b0[j]);
  ln_relu<16>(a0, P.g0, P.be0);
  float a1[32]; linear_full<16, 32>(a0, P.W1, P.b1, a1); ln_relu<32>(a1, P.g1, P.be1);
  float a2[64]; linear_full<32, 64>(a1, P.W2, P.b2, a2); ln_relu<64>(a2, P.g2, P.be2);
  float a3[128]; linear_full<64, 128>(a2, P.W3, P.b3, a3); ln_relu<128>(a3, P.g3, P.be3);
  float a4[64]; linear_full<128, 64>(a3, P.W4, P.b4, a4); ln_relu<64>(a4, P.g4, P.be4);
  float a5[32]; linear_full<64, 32>(a4, P.W5, P.b5, a5); ln_relu<32>(a5, P.g5, P.be5);
  float y0 = P.b6[0], y1 = 0.f, y2 = 0.f, y3 = 0.f;
  #pragma unroll
  for (int i = 0; i < 32; i += 4) {
    y0 = fmaf(a5[i],   P.W6[i],   y0);
    y1 = fmaf(a5[i+1], P.W6[i+1], y1);
    y2 = fmaf(a5[i+2], P.W6[i+2], y2);
    y3 = fmaf(a5[i+3], P.W6[i+3], y3);
  }
  return (y0 + y1) + (y2 + y3);
}

// ---------- range derivation (identical fp32 arithmetic in build & lookup) ----------
__device__ __forceinline__ void get_range(const unsigned* __restrict__ mm,
                                          float& lo, float& step, float& istep) {
  float fmin = dec_f(mm[0]) - 1e-3f;
  float fmax = dec_f(mm[1]) + 1e-3f;
  lo = fmin;
  float span = fmax - fmin;
  step  = span * (1.0f / (float)(TPTS - 1));
  istep = (float)(TPTS - 1) / span;
}

// ---------- kernels ----------
__global__ void init_kernel(unsigned* mm) {
  mm[0] = 0xFFFFFFFFu;  // min key
  mm[1] = 0u;           // max key
}

__global__ __launch_bounds__(256) void minmax_kernel(const float* __restrict__ x,
                                                     unsigned* mm, int n) {
  int tid = blockIdx.x * blockDim.x + threadIdx.x;
  int stride = gridDim.x * blockDim.x;
  float lmin = 3.0e38f, lmax = -3.0e38f;
  for (int i = tid * 4; i + 3 < n; i += stride * 4) {
    float4 v = *reinterpret_cast<const float4*>(x + i);
    lmin = fminf(lmin, fminf(fminf(v.x, v.y), fminf(v.z, v.w)));
    lmax = fmaxf(lmax, fmaxf(fmaxf(v.x, v.y), fmaxf(v.z, v.w)));
  }
  if (tid == 0) {  // tail if n % 4 != 0
    for (int i = n & ~3; i < n; ++i) {
      lmin = fminf(lmin, x[i]);
      lmax = fmaxf(lmax, x[i]);
    }
  }
  #pragma unroll
  for (int off = 32; off > 0; off >>= 1) {
    lmin = fminf(lmin, __shfl_xor(lmin, off));
    lmax = fmaxf(lmax, __shfl_xor(lmax, off));
  }
  if ((threadIdx.x & 63) == 0) {
    atomicMin(&mm[0], enc_f(lmin));
    atomicMax(&mm[1], enc_f(lmax));
  }
}

// waves_per_eu(1,1): cap occupancy at 1 wave/EU -> register budget 512 VGPRs.
// launch_bounds(256,1)'s 2nd arg is only a MIN-waves promise and did NOT lift
// the allocator's default ~4-wave budget -> 144 VGPRs + 1.6 GB scratch spill
// (round-2 counters). The ~200-float live set of eval_chain needs the cap.
__global__ __launch_bounds__(256)
__attribute__((amdgpu_waves_per_eu(1, 1)))
void build_kernel(float* __restrict__ table,
                  const unsigned* __restrict__ mm,
                  Params P) {
  int idx = blockIdx.x * blockDim.x + threadIdx.x;
  float lo, step, istep;
  get_range(mm, lo, step, istep);
  float x = fmaf((float)idx, step, lo);
  table[idx] = eval_chain(x, P);
}

__device__ __forceinline__ float interp(float xv, float lo, float istep,
                                        const float* __restrict__ t) {
  float tt = (xv - lo) * istep;
  tt = fminf(fmaxf(tt, 0.0f), (float)(TPTS - 1));
  int i = (int)tt;
  if (i > TPTS - 2) i = TPTS - 2;
  float f = tt - (float)i;
  float t0 = t[i], t1 = t[i + 1];
  return fmaf(f, t1 - t0, t0);
}

__global__ __launch_bounds__(256) void lookup_kernel(const float* __restrict__ x,
                                                     const float* __restrict__ table,
                                                     const unsigned* __restrict__ mm,
                                                     float* __restrict__ out, int n) {
  float lo, step, istep;
  get_range(mm, lo, step, istep);
  int tid = blockIdx.x * blockDim.x + threadIdx.x;
  int stride = gridDim.x * blockDim.x;
  for (int i = tid * 4; i + 3 < n; i += stride * 4) {
    float4 v = *reinterpret_cast<const float4*>(x + i);
    float4 r;
    r.x = interp(v.x, lo, istep, table);
    r.y = interp(v.y, lo, istep, table);
    r.z = interp(v.z, lo, istep, table);
    r.w = interp(v.w, lo, istep, table);
    *reinterpret_cast<float4*>(out + i) = r;
  }
  if (tid == 0) {  // tail if n % 4 != 0
    for (int i = n & ~3; i < n; ++i) out[i] = interp(x[i], lo, istep, table);
  }
}

// Fallback: direct per-element evaluation (used only if workspace too small)
__global__ __launch_bounds__(256)
__attribute__((amdgpu_waves_per_eu(1, 1)))
void direct_kernel(const float* __restrict__ x,
                   Params P, float* __restrict__ out,
                   int n) {
  int tid = blockIdx.x * blockDim.x + threadIdx.x;
  int stride = gridDim.x * blockDim.x;
  for (int i = tid; i < n; i += stride) out[i] = eval_chain(x[i], P);
}

extern "C" void kernel_launch(void* const* d_in, const int* in_sizes, int n_in,
                              void* d_out, int out_size, void* d_ws, size_t ws_size,
                              hipStream_t stream) {
  const float* x = (const float*)d_in[0];
  Params P;
  P.W0 = (const float*)d_in[1];  P.b0 = (const float*)d_in[2];
  P.W1 = (const float*)d_in[3];  P.b1 = (const float*)d_in[4];
  P.W2 = (const float*)d_in[5];  P.b2 = (const float*)d_in[6];
  P.W3 = (const float*)d_in[7];  P.b3 = (const float*)d_in[8];
  P.W4 = (const float*)d_in[9];  P.b4 = (const float*)d_in[10];
  P.W5 = (const float*)d_in[11]; P.b5 = (const float*)d_in[12];
  P.W6 = (const float*)d_in[13]; P.b6 = (const float*)d_in[14];
  P.g0 = (const float*)d_in[15]; P.be0 = (const float*)d_in[16];
  P.g1 = (const float*)d_in[17]; P.be1 = (const float*)d_in[18];
  P.g2 = (const float*)d_in[19]; P.be2 = (const float*)d_in[20];
  P.g3 = (const float*)d_in[21]; P.be3 = (const float*)d_in[22];
  P.g4 = (const float*)d_in[23]; P.be4 = (const float*)d_in[24];
  P.g5 = (const float*)d_in[25]; P.be5 = (const float*)d_in[26];

  int n = in_sizes[0];
  float* out = (float*)d_out;

  size_t need = 256 + (size_t)TPTS * sizeof(float);
  if (ws_size < need) {
    direct_kernel<<<2048, 256, 0, stream>>>(x, P, out, n);
    return;
  }

  unsigned* mm = (unsigned*)d_ws;
  float* table = (float*)((char*)d_ws + 256);

  init_kernel<<<1, 1, 0, stream>>>(mm);
  minmax_kernel<<<512, 256, 0, stream>>>(x, mm, n);
  build_kernel<<<TPTS / 256, 256, 0, stream>>>(table, mm, P);
  lookup_kernel<<<1024, 256, 0, stream>>>(x, table, mm, out, n);
}

// Round 4
// 413.927 us; speedup vs baseline: 1.9381x; 1.1691x over previous
//
#include <hip/hip_runtime.h>
#include <math.h>

#define EPS_LN 1e-5f
#define TPTS 65536
#define ROWS 128  // threads per block == table rows per block; a3 LDS = 128*128*4 = 64 KB

struct Params {
  const float *W0,*b0,*W1,*b1,*W2,*b2,*W3,*b3,*W4,*b4,*W5,*b5,*W6,*b6;
  const float *g0,*be0,*g1,*be1,*g2,*be2,*g3,*be3,*g4,*be4,*g5,*be5;
};

// ---------- order-preserving float<->uint for atomic min/max ----------
__device__ __forceinline__ unsigned enc_f(float f) {
  unsigned u = __float_as_uint(f);
  return (u & 0x80000000u) ? ~u : (u | 0x80000000u);
}
__device__ __forceinline__ float dec_f(unsigned k) {
  unsigned u = (k & 0x80000000u) ? (k ^ 0x80000000u) : ~k;
  return __uint_as_float(u);
}

// ---------- register-resident building blocks (all static indexing) ----------
template<int IN, int OUT>
__device__ __forceinline__ void linear_full(const float* hin, const float* __restrict__ W,
                                            const float* __restrict__ b, float* hout) {
  #pragma unroll
  for (int j = 0; j < OUT; ++j) hout[j] = b[j];
  #pragma unroll
  for (int i = 0; i < IN; ++i) {
    float v = hin[i];
    #pragma unroll
    for (int j = 0; j < OUT; ++j) hout[j] = fmaf(v, W[i * OUT + j], hout[j]);
  }
}

template<int D>
__device__ __forceinline__ void ln_relu(float* h, const float* __restrict__ g,
                                        const float* __restrict__ be) {
  float s0 = 0.f, s1 = 0.f, s2 = 0.f, s3 = 0.f;
  #pragma unroll
  for (int j = 0; j < D; j += 4) { s0 += h[j]; s1 += h[j+1]; s2 += h[j+2]; s3 += h[j+3]; }
  float m = ((s0 + s1) + (s2 + s3)) * (1.0f / (float)D);
  float v0 = 0.f, v1 = 0.f, v2 = 0.f, v3 = 0.f;
  #pragma unroll
  for (int j = 0; j < D; j += 4) {
    float d0 = h[j] - m, d1 = h[j+1] - m, d2 = h[j+2] - m, d3 = h[j+3] - m;
    v0 = fmaf(d0, d0, v0); v1 = fmaf(d1, d1, v1);
    v2 = fmaf(d2, d2, v2); v3 = fmaf(d3, d3, v3);
  }
  float var = ((v0 + v1) + (v2 + v3)) * (1.0f / (float)D);
  float sc = rsqrtf(var + EPS_LN);
  #pragma unroll
  for (int j = 0; j < D; ++j) {
    float t = (h[j] - m) * sc;
    t = fmaf(t, g[j], be[j]);
    h[j] = fmaxf(t, 0.0f);
  }
}

// ---------- range derivation (identical fp32 arithmetic in build & lookup) ----------
__device__ __forceinline__ void get_range(const unsigned* __restrict__ mm,
                                          float& lo, float& step, float& istep) {
  float fmin = dec_f(mm[0]) - 1e-3f;
  float fmax = dec_f(mm[1]) + 1e-3f;
  lo = fmin;
  float span = fmax - fmin;
  step  = span * (1.0f / (float)(TPTS - 1));
  istep = (float)(TPTS - 1) / span;
}

// ---------- kernels ----------
__global__ void init_kernel(unsigned* mm) {
  mm[0] = 0xFFFFFFFFu;  // min key
  mm[1] = 0u;           // max key
}

__global__ __launch_bounds__(256) void minmax_kernel(const float* __restrict__ x,
                                                     unsigned* mm, int n) {
  int tid = blockIdx.x * blockDim.x + threadIdx.x;
  int stride = gridDim.x * blockDim.x;
  float lmin = 3.0e38f, lmax = -3.0e38f;
  for (int i = tid * 4; i + 3 < n; i += stride * 4) {
    float4 v = *reinterpret_cast<const float4*>(x + i);
    lmin = fminf(lmin, fminf(fminf(v.x, v.y), fminf(v.z, v.w)));
    lmax = fmaxf(lmax, fmaxf(fmaxf(v.x, v.y), fmaxf(v.z, v.w)));
  }
  if (tid == 0) {  // tail if n % 4 != 0
    for (int i = n & ~3; i < n; ++i) {
      lmin = fminf(lmin, x[i]);
      lmax = fmaxf(lmax, x[i]);
    }
  }
  #pragma unroll
  for (int off = 32; off > 0; off >>= 1) {
    lmin = fminf(lmin, __shfl_xor(lmin, off));
    lmax = fmaxf(lmax, __shfl_xor(lmax, off));
  }
  if ((threadIdx.x & 63) == 0) {
    atomicMin(&mm[0], enc_f(lmin));
    atomicMax(&mm[1], enc_f(lmax));
  }
}

// Live set kept <= ~110 VGPR by construction: only a3 (128 floats) leaves the
// register file, into a DIM-MAJOR LDS tile a3s[dim][thread] — lanes access
// consecutive dwords -> 2-way bank aliasing (free). Each thread touches only
// its own column: no barriers. r3's compiler-chosen ROW-major LDS spill gave
// 9.6e7 bank-conflict cycles (~46% of kernel time); this removes it.
__global__ __launch_bounds__(ROWS)
__attribute__((amdgpu_waves_per_eu(1, 1)))
void build_kernel(float* __restrict__ table,
                  const unsigned* __restrict__ mm,
                  Params P) {
  __shared__ float a3s[128][ROWS];
  const int t = threadIdx.x;
  const int idx = blockIdx.x * ROWS + t;
  float lo, step, istep;
  get_range(mm, lo, step, istep);
  const float x = fmaf((float)idx, step, lo);

  // L0: 1 -> 16, LN+ReLU
  float a0[16];
  #pragma unroll
  for (int j = 0; j < 16; ++j) a0[j] = fmaf(x, P.W0[j], P.b0[j]);
  ln_relu<16>(a0, P.g0, P.be0);
  // L1: 16 -> 32
  float a1[32]; linear_full<16, 32>(a0, P.W1, P.b1, a1); ln_relu<32>(a1, P.g1, P.be1);
  // L2: 32 -> 64
  float a2[64]; linear_full<32, 64>(a1, P.W2, P.b2, a2); ln_relu<64>(a2, P.g2, P.be2);

  // L3: 64 -> 128, in 4 chunks of 32 register accumulators, streamed to LDS
  #pragma unroll
  for (int c = 0; c < 4; ++c) {
    float acc[32];
    #pragma unroll
    for (int j = 0; j < 32; ++j) acc[j] = P.b3[c * 32 + j];
    #pragma unroll
    for (int i = 0; i < 64; ++i) {
      float v = a2[i];
      #pragma unroll
      for (int j = 0; j < 32; ++j)
        acc[j] = fmaf(v, P.W3[i * 128 + c * 32 + j], acc[j]);
    }
    #pragma unroll
    for (int j = 0; j < 32; ++j) a3s[c * 32 + j][t] = acc[j];
  }

  // LN stats over a3 (this thread's column), two-pass like the reference
  float s0 = 0.f, s1 = 0.f, s2 = 0.f, s3 = 0.f;
  #pragma unroll
  for (int i = 0; i < 128; i += 4) {
    s0 += a3s[i][t];     s1 += a3s[i + 1][t];
    s2 += a3s[i + 2][t]; s3 += a3s[i + 3][t];
  }
  const float m3 = ((s0 + s1) + (s2 + s3)) * (1.0f / 128.0f);
  float v0 = 0.f, v1 = 0.f, v2 = 0.f, v3 = 0.f;
  #pragma unroll
  for (int i = 0; i < 128; i += 4) {
    float d0 = a3s[i][t] - m3,     d1 = a3s[i + 1][t] - m3;
    float d2 = a3s[i + 2][t] - m3, d3 = a3s[i + 3][t] - m3;
    v0 = fmaf(d0, d0, v0); v1 = fmaf(d1, d1, v1);
    v2 = fmaf(d2, d2, v2); v3 = fmaf(d3, d3, v3);
  }
  const float var3 = ((v0 + v1) + (v2 + v3)) * (1.0f / 128.0f);
  const float sc3 = rsqrtf(var3 + EPS_LN);

  // L4: 128 -> 64, LN+ReLU applied to a3 on the fly while streaming from LDS
  float a4[64];
  #pragma unroll
  for (int j = 0; j < 64; ++j) a4[j] = P.b4[j];
  #pragma unroll
  for (int i = 0; i < 128; ++i) {
    float v = a3s[i][t];
    float h = (v - m3) * sc3;
    h = fmaf(h, P.g3[i], P.be3[i]);
    h = fmaxf(h, 0.0f);
    #pragma unroll
    for (int j = 0; j < 64; ++j) a4[j] = fmaf(h, P.W4[i * 64 + j], a4[j]);
  }
  ln_relu<64>(a4, P.g4, P.be4);

  // L5: 64 -> 32
  float a5[32]; linear_full<64, 32>(a4, P.W5, P.b5, a5); ln_relu<32>(a5, P.g5, P.be5);

  // L6: 32 -> 1
  float y0 = P.b6[0], y1 = 0.f, y2 = 0.f, y3 = 0.f;
  #pragma unroll
  for (int i = 0; i < 32; i += 4) {
    y0 = fmaf(a5[i],   P.W6[i],   y0);
    y1 = fmaf(a5[i+1], P.W6[i+1], y1);
    y2 = fmaf(a5[i+2], P.W6[i+2], y2);
    y3 = fmaf(a5[i+3], P.W6[i+3], y3);
  }
  table[idx] = (y0 + y1) + (y2 + y3);
}

__device__ __forceinline__ float interp(float xv, float lo, float istep,
                                        const float* __restrict__ t) {
  float tt = (xv - lo) * istep;
  tt = fminf(fmaxf(tt, 0.0f), (float)(TPTS - 1));
  int i = (int)tt;
  if (i > TPTS - 2) i = TPTS - 2;
  float f = tt - (float)i;
  float t0 = t[i], t1 = t[i + 1];
  return fmaf(f, t1 - t0, t0);
}

__global__ __launch_bounds__(256) void lookup_kernel(const float* __restrict__ x,
                                                     const float* __restrict__ table,
                                                     const unsigned* __restrict__ mm,
                                                     float* __restrict__ out, int n) {
  float lo, step, istep;
  get_range(mm, lo, step, istep);
  int tid = blockIdx.x * blockDim.x + threadIdx.x;
  int stride = gridDim.x * blockDim.x;
  for (int i = tid * 4; i + 3 < n; i += stride * 4) {
    float4 v = *reinterpret_cast<const float4*>(x + i);
    float4 r;
    r.x = interp(v.x, lo, istep, table);
    r.y = interp(v.y, lo, istep, table);
    r.z = interp(v.z, lo, istep, table);
    r.w = interp(v.w, lo, istep, table);
    *reinterpret_cast<float4*>(out + i) = r;
  }
  if (tid == 0) {  // tail if n % 4 != 0
    for (int i = n & ~3; i < n; ++i) out[i] = interp(x[i], lo, istep, table);
  }
}

extern "C" void kernel_launch(void* const* d_in, const int* in_sizes, int n_in,
                              void* d_out, int out_size, void* d_ws, size_t ws_size,
                              hipStream_t stream) {
  const float* x = (const float*)d_in[0];
  Params P;
  P.W0 = (const float*)d_in[1];  P.b0 = (const float*)d_in[2];
  P.W1 = (const float*)d_in[3];  P.b1 = (const float*)d_in[4];
  P.W2 = (const float*)d_in[5];  P.b2 = (const float*)d_in[6];
  P.W3 = (const float*)d_in[7];  P.b3 = (const float*)d_in[8];
  P.W4 = (const float*)d_in[9];  P.b4 = (const float*)d_in[10];
  P.W5 = (const float*)d_in[11]; P.b5 = (const float*)d_in[12];
  P.W6 = (const float*)d_in[13]; P.b6 = (const float*)d_in[14];
  P.g0 = (const float*)d_in[15]; P.be0 = (const float*)d_in[16];
  P.g1 = (const float*)d_in[17]; P.be1 = (const float*)d_in[18];
  P.g2 = (const float*)d_in[19]; P.be2 = (const float*)d_in[20];
  P.g3 = (const float*)d_in[21]; P.be3 = (const float*)d_in[22];
  P.g4 = (const float*)d_in[23]; P.be4 = (const float*)d_in[24];
  P.g5 = (const float*)d_in[25]; P.be5 = (const float*)d_in[26];

  int n = in_sizes[0];
  float* out = (float*)d_out;

  unsigned* mm = (unsigned*)d_ws;
  float* table = (float*)((char*)d_ws + 256);

  init_kernel<<<1, 1, 0, stream>>>(mm);
  minmax_kernel<<<512, 256, 0, stream>>>(x, mm, n);
  build_kernel<<<TPTS / ROWS, ROWS, 0, stream>>>(table, mm, P);
  lookup_kernel<<<1024, 256, 0, stream>>>(x, table, mm, out, n);
}

// Round 5
// 405.372 us; speedup vs baseline: 1.9790x; 1.0211x over previous
//
#include <hip/hip_runtime.h>
#include <math.h>

#define EPS_LN 1e-5f
#define TPTS 65536

struct Params {
  const float *W0,*b0,*W1,*b1,*W2,*b2,*W3,*b3,*W4,*b4,*W5,*b5,*W6,*b6;
  const float *g0,*be0,*g1,*be1,*g2,*be2,*g3,*be3,*g4,*be4,*g5,*be5;
};

// ---------- order-preserving float<->uint for atomic min/max ----------
__device__ __forceinline__ unsigned enc_f(float f) {
  unsigned u = __float_as_uint(f);
  return (u & 0x80000000u) ? ~u : (u | 0x80000000u);
}
__device__ __forceinline__ float dec_f(unsigned k) {
  unsigned u = (k & 0x80000000u) ? (k ^ 0x80000000u) : ~k;
  return __uint_as_float(u);
}

// ---------- 8-lane-group primitives ----------
// Sum across the 8-lane group (groups are 8-aligned; xor masks <8 stay in-group).
__device__ __forceinline__ float gred8(float v) {
  v += __shfl_xor(v, 1);
  v += __shfl_xor(v, 2);
  v += __shfl_xor(v, 4);
  return v;
}

// Linear layer with activations sliced 8 ways (blocked): lane r owns output
// dims [r*OUT/8, (r+1)*OUT/8). Inputs broadcast via shfl — i is fully
// unrolled so hin[i % INP] is a STATIC register index (rule: no runtime
// indexing of register arrays).
template<int IN, int OUT>
__device__ __forceinline__ void linear8(const float* hin, const float* __restrict__ W,
                                        const float* __restrict__ b, int r, float* hout) {
  constexpr int INP = IN / 8, OUTP = OUT / 8;
  #pragma unroll
  for (int j = 0; j < OUTP; ++j) hout[j] = b[r * OUTP + j];
  #pragma unroll
  for (int i = 0; i < IN; ++i) {
    float v = __shfl(hin[i % INP], i / INP, 8);
    const float* Wr = W + i * OUT + r * OUTP;
    #pragma unroll
    for (int j4 = 0; j4 < OUTP; j4 += 4) {
      float4 w = *reinterpret_cast<const float4*>(Wr + j4);
      hout[j4 + 0] = fmaf(v, w.x, hout[j4 + 0]);
      hout[j4 + 1] = fmaf(v, w.y, hout[j4 + 1]);
      hout[j4 + 2] = fmaf(v, w.z, hout[j4 + 2]);
      hout[j4 + 3] = fmaf(v, w.w, hout[j4 + 3]);
    }
  }
}

// LayerNorm+ReLU over D dims sliced across the 8-lane group (D/8 per lane).
// Two-pass (mean, then biased var) like the reference.
template<int D>
__device__ __forceinline__ void ln_relu8(float* h, int r,
                                         const float* __restrict__ g,
                                         const float* __restrict__ be) {
  constexpr int DP = D / 8;
  float s = 0.f;
  #pragma unroll
  for (int j = 0; j < DP; ++j) s += h[j];
  const float m = gred8(s) * (1.0f / (float)D);
  float vs = 0.f;
  #pragma unroll
  for (int j = 0; j < DP; ++j) { float d = h[j] - m; vs = fmaf(d, d, vs); }
  const float var = gred8(vs) * (1.0f / (float)D);
  const float sc = rsqrtf(var + EPS_LN);
  #pragma unroll
  for (int j = 0; j < DP; ++j) {
    float t = (h[j] - m) * sc;
    t = fmaf(t, g[r * DP + j], be[r * DP + j]);
    h[j] = fmaxf(t, 0.0f);
  }
}

// ---------- range derivation (identical fp32 arithmetic in build & lookup) ----------
__device__ __forceinline__ void get_range(const unsigned* __restrict__ mm,
                                          float& lo, float& step, float& istep) {
  float fmin = dec_f(mm[0]) - 1e-3f;
  float fmax = dec_f(mm[1]) + 1e-3f;
  lo = fmin;
  float span = fmax - fmin;
  step  = span * (1.0f / (float)(TPTS - 1));
  istep = (float)(TPTS - 1) / span;
}

// ---------- kernels ----------
__global__ void init_kernel(unsigned* mm) {
  mm[0] = 0xFFFFFFFFu;  // min key
  mm[1] = 0u;           // max key
}

__global__ __launch_bounds__(256) void minmax_kernel(const float* __restrict__ x,
                                                     unsigned* mm, int n) {
  int tid = blockIdx.x * blockDim.x + threadIdx.x;
  int stride = gridDim.x * blockDim.x;
  float lmin = 3.0e38f, lmax = -3.0e38f;
  for (int i = tid * 4; i + 3 < n; i += stride * 4) {
    float4 v = *reinterpret_cast<const float4*>(x + i);
    lmin = fminf(lmin, fminf(fminf(v.x, v.y), fminf(v.z, v.w)));
    lmax = fmaxf(lmax, fmaxf(fmaxf(v.x, v.y), fmaxf(v.z, v.w)));
  }
  if (tid == 0) {  // tail if n % 4 != 0
    for (int i = n & ~3; i < n; ++i) {
      lmin = fminf(lmin, x[i]);
      lmax = fmaxf(lmax, x[i]);
    }
  }
  #pragma unroll
  for (int off = 32; off > 0; off >>= 1) {
    lmin = fminf(lmin, __shfl_xor(lmin, off));
    lmax = fmaxf(lmax, __shfl_xor(lmax, off));
  }
  if ((threadIdx.x & 63) == 0) {
    atomicMin(&mm[0], enc_f(lmin));
    atomicMax(&mm[1], enc_f(lmax));
  }
}

// 8 lanes per table point. r3/r4 showed the one-point-per-thread grid caps at
// 4 waves/CU (OccupancyPercent 12, VALUBusy 17 — latency-bound with nothing
// to hide it). Splitting each point 8 ways: 8192 waves = 32 waves/CU, live
// set ~45 VGPR, zero LDS. Extra cost is ~310 shfl + 8x-redundant small
// layers (~1.3x wave-cycles) — repaid 6-8x by occupancy.
__global__ __launch_bounds__(256)
__attribute__((amdgpu_waves_per_eu(4, 8)))
void build_kernel(float* __restrict__ table,
                  const unsigned* __restrict__ mm,
                  Params P) {
  const int tid = blockIdx.x * 256 + threadIdx.x;
  const int point = tid >> 3;
  const int r = tid & 7;
  float lo, step, istep;
  get_range(mm, lo, step, istep);
  const float x = fmaf((float)point, step, lo);

  // L0: 1 -> 16 (2 dims per lane)
  float a0[2];
  #pragma unroll
  for (int j = 0; j < 2; ++j) a0[j] = fmaf(x, P.W0[r * 2 + j], P.b0[r * 2 + j]);
  ln_relu8<16>(a0, r, P.g0, P.be0);

  float a1[4];  linear8<16, 32>(a0, P.W1, P.b1, r, a1);  ln_relu8<32>(a1, r, P.g1, P.be1);
  float a2[8];  linear8<32, 64>(a1, P.W2, P.b2, r, a2);  ln_relu8<64>(a2, r, P.g2, P.be2);
  float a3[16]; linear8<64, 128>(a2, P.W3, P.b3, r, a3); ln_relu8<128>(a3, r, P.g3, P.be3);
  float a4[8];  linear8<128, 64>(a3, P.W4, P.b4, r, a4); ln_relu8<64>(a4, r, P.g4, P.be4);
  float a5[4];  linear8<64, 32>(a4, P.W5, P.b5, r, a5);  ln_relu8<32>(a5, r, P.g5, P.be5);

  // L6: 32 -> 1 (4 partials per lane, group-reduce)
  float part = 0.f;
  #pragma unroll
  for (int j = 0; j < 4; ++j) part = fmaf(a5[j], P.W6[r * 4 + j], part);
  part = gred8(part);
  if (r == 0) table[point] = part + P.b6[0];
}

__device__ __forceinline__ float interp(float xv, float lo, float istep,
                                        const float* __restrict__ t) {
  float tt = (xv - lo) * istep;
  tt = fminf(fmaxf(tt, 0.0f), (float)(TPTS - 1));
  int i = (int)tt;
  if (i > TPTS - 2) i = TPTS - 2;
  float f = tt - (float)i;
  float t0 = t[i], t1 = t[i + 1];
  return fmaf(f, t1 - t0, t0);
}

__global__ __launch_bounds__(256) void lookup_kernel(const float* __restrict__ x,
                                                     const float* __restrict__ table,
                                                     const unsigned* __restrict__ mm,
                                                     float* __restrict__ out, int n) {
  float lo, step, istep;
  get_range(mm, lo, step, istep);
  int tid = blockIdx.x * blockDim.x + threadIdx.x;
  int stride = gridDim.x * blockDim.x;
  for (int i = tid * 4; i + 3 < n; i += stride * 4) {
    float4 v = *reinterpret_cast<const float4*>(x + i);
    float4 r;
    r.x = interp(v.x, lo, istep, table);
    r.y = interp(v.y, lo, istep, table);
    r.z = interp(v.z, lo, istep, table);
    r.w = interp(v.w, lo, istep, table);
    *reinterpret_cast<float4*>(out + i) = r;
  }
  if (tid == 0) {  // tail if n % 4 != 0
    for (int i = n & ~3; i < n; ++i) out[i] = interp(x[i], lo, istep, table);
  }
}

extern "C" void kernel_launch(void* const* d_in, const int* in_sizes, int n_in,
                              void* d_out, int out_size, void* d_ws, size_t ws_size,
                              hipStream_t stream) {
  const float* x = (const float*)d_in[0];
  Params P;
  P.W0 = (const float*)d_in[1];  P.b0 = (const float*)d_in[2];
  P.W1 = (const float*)d_in[3];  P.b1 = (const float*)d_in[4];
  P.W2 = (const float*)d_in[5];  P.b2 = (const float*)d_in[6];
  P.W3 = (const float*)d_in[7];  P.b3 = (const float*)d_in[8];
  P.W4 = (const float*)d_in[9];  P.b4 = (const float*)d_in[10];
  P.W5 = (const float*)d_in[11]; P.b5 = (const float*)d_in[12];
  P.W6 = (const float*)d_in[13]; P.b6 = (const float*)d_in[14];
  P.g0 = (const float*)d_in[15]; P.be0 = (const float*)d_in[16];
  P.g1 = (const float*)d_in[17]; P.be1 = (const float*)d_in[18];
  P.g2 = (const float*)d_in[19]; P.be2 = (const float*)d_in[20];
  P.g3 = (const float*)d_in[21]; P.be3 = (const float*)d_in[22];
  P.g4 = (const float*)d_in[23]; P.be4 = (const float*)d_in[24];
  P.g5 = (const float*)d_in[25]; P.be5 = (const float*)d_in[26];

  int n = in_sizes[0];
  float* out = (float*)d_out;

  unsigned* mm = (unsigned*)d_ws;
  float* table = (float*)((char*)d_ws + 256);

  init_kernel<<<1, 1, 0, stream>>>(mm);
  minmax_kernel<<<512, 256, 0, stream>>>(x, mm, n);
  build_kernel<<<(TPTS * 8) / 256, 256, 0, stream>>>(table, mm, P);
  lookup_kernel<<<1024, 256, 0, stream>>>(x, table, mm, out, n);
}